// Round 5
// baseline (1194.403 us; speedup 1.0000x reference)
//
#include <hip/hip_runtime.h>

typedef short bf16x8 __attribute__((ext_vector_type(8)));
typedef float f32x4 __attribute__((ext_vector_type(4)));

#define LN10000_32 0.2878231406211853f  // ln(10000)/32

__device__ __forceinline__ unsigned short f2bf(float f) {
  union { float f; unsigned int u; } v; v.f = f;
  unsigned int r = v.u + 0x7fffu + ((v.u >> 16) & 1u);
  return (unsigned short)(r >> 16);
}
__device__ __forceinline__ float bf2f(unsigned short h) {
  union { unsigned int u; float f; } v; v.u = ((unsigned int)h) << 16;
  return v.f;
}

__device__ __forceinline__ void stage16(const unsigned short* g, unsigned short* lds_base, int lane) {
#if __has_builtin(__builtin_amdgcn_global_load_lds)
  (void)lane;
  __builtin_amdgcn_global_load_lds((const __attribute__((address_space(1))) void*)g,
                                   (__attribute__((address_space(3))) void*)lds_base,
                                   16, 0, 0);
#else
  *(bf16x8*)((char*)lds_base + lane * 16) = *(const bf16x8*)g;
#endif
}

// ---------------- min/max of the two x_ref_attn_map rows ---------------------
__global__ void minmax_kernel(const float* __restrict__ xmap, float* __restrict__ mm) {
  __shared__ float red[4][256];
  int t = threadIdx.x;
  float mn0 = 3.4e38f, mx0 = -3.4e38f, mn1 = 3.4e38f, mx1 = -3.4e38f;
  for (int i = t; i < 32760; i += 256) {
    float a = xmap[i];          mn0 = fminf(mn0, a); mx0 = fmaxf(mx0, a);
    float b = xmap[32760 + i];  mn1 = fminf(mn1, b); mx1 = fmaxf(mx1, b);
  }
  red[0][t] = mn0; red[1][t] = mx0; red[2][t] = mn1; red[3][t] = mx1;
  __syncthreads();
  for (int s = 128; s > 0; s >>= 1) {
    if (t < s) {
      red[0][t] = fminf(red[0][t], red[0][t + s]);
      red[1][t] = fmaxf(red[1][t], red[1][t + s]);
      red[2][t] = fminf(red[2][t], red[2][t + s]);
      red[3][t] = fmaxf(red[3][t], red[3][t + s]);
    }
    __syncthreads();
  }
  if (t == 0) { mm[0] = red[0][0]; mm[1] = red[1][0]; mm[2] = red[2][0]; mm[3] = red[3][0]; }
}

// ---------------- normalized position -> cos/sin table (32760 x 32) ----------
__global__ void pos_table_kernel(const float* __restrict__ xmap, const float* __restrict__ mm,
                                 float2* __restrict__ tab) {
  int n = blockIdx.x * 256 + threadIdx.x;
  if (n >= 32760) return;
  float m0 = xmap[n], m1 = xmap[32760 + n];
  float pos;
  if (m1 > m0) pos = (m1 - mm[2]) / (mm[3] - mm[2] + 1e-8f) * 4.0f + 20.0f;
  else         pos = (m0 - mm[0]) / (mm[1] - mm[0] + 1e-8f) * 4.0f;
  #pragma unroll
  for (int j = 0; j < 32; j++) {
    float invf = __expf(-(float)j * LN10000_32);
    float f = pos * invf;
    float s, c;
    sincosf(f, &s, &c);
    tab[(long)n * 32 + j] = make_float2(c, s);
  }
}

// ---------------- casts -------------------------------------------------------
__global__ void cast_x_kernel(const float* __restrict__ src, unsigned short* __restrict__ dst) {
  int r = blockIdx.x;
  int c = threadIdx.x * 8;
  bf16x8 o;
  if (r < 32760) {
    const float4* s = (const float4*)(src + (long)r * 2048 + c);
    float4 a = s[0], b = s[1];
    o[0] = (short)f2bf(a.x); o[1] = (short)f2bf(a.y); o[2] = (short)f2bf(a.z); o[3] = (short)f2bf(a.w);
    o[4] = (short)f2bf(b.x); o[5] = (short)f2bf(b.y); o[6] = (short)f2bf(b.z); o[7] = (short)f2bf(b.w);
  } else {
    #pragma unroll
    for (int t = 0; t < 8; t++) o[t] = 0;
  }
  *(bf16x8*)(dst + (long)r * 2048 + c) = o;
}

__global__ void cast_flat_kernel(const float* __restrict__ src, unsigned short* __restrict__ dst, long n8) {
  long i = (long)blockIdx.x * 256 + threadIdx.x;
  if (i >= n8) return;
  const float4* s = (const float4*)(src + i * 8);
  float4 a = s[0], b = s[1];
  bf16x8 o;
  o[0] = (short)f2bf(a.x); o[1] = (short)f2bf(a.y); o[2] = (short)f2bf(a.z); o[3] = (short)f2bf(a.w);
  o[4] = (short)f2bf(b.x); o[5] = (short)f2bf(b.y); o[6] = (short)f2bf(b.z); o[7] = (short)f2bf(b.w);
  *(bf16x8*)(dst + i * 8) = o;
}

__global__ void cast_ehs_kernel(const float* __restrict__ src, unsigned short* __restrict__ dst) {
  int idx = blockIdx.x * 256 + threadIdx.x;
  int r = idx / 96, c = (idx % 96) * 8;
  bf16x8 o;
  if (r < 672) {
    const float4* s = (const float4*)(src + (long)r * 768 + c);
    float4 a = s[0], b = s[1];
    o[0] = (short)f2bf(a.x); o[1] = (short)f2bf(a.y); o[2] = (short)f2bf(a.z); o[3] = (short)f2bf(a.w);
    o[4] = (short)f2bf(b.x); o[5] = (short)f2bf(b.y); o[6] = (short)f2bf(b.z); o[7] = (short)f2bf(b.w);
  } else {
    #pragma unroll
    for (int t = 0; t < 8; t++) o[t] = 0;
  }
  *(bf16x8*)(dst + (long)r * 768 + c) = o;
}

// ---------------- small GEMM (128x128 m97-style) for KV projection -----------
template <int OUTF>
__global__ __launch_bounds__(256, 2)
void gemm_bt(const unsigned short* __restrict__ A, const unsigned short* __restrict__ B,
             const float* __restrict__ bias, void* __restrict__ C,
             int M, int N, int K, int M_valid) {
  __shared__ unsigned short As[128 * 32];
  __shared__ unsigned short Bs[128 * 32];
  int mt = blockIdx.x, nt = blockIdx.y;
  const int m0 = mt * 128;
  const int n0 = nt * 128;
  const int tid = threadIdx.x;
  const int wave = tid >> 6;
  const int lane = tid & 63;
  const int wr = wave >> 1, wc = wave & 1;
  const int lrow = lane >> 2, lcol = lane & 3;

  f32x4 acc[4][4];
  #pragma unroll
  for (int i = 0; i < 4; i++)
    #pragma unroll
    for (int j = 0; j < 4; j++) acc[i][j] = (f32x4){0.f, 0.f, 0.f, 0.f};

  const unsigned short* gA = A + (long)(m0 + wave * 32 + lrow) * K + lcol * 8;
  const unsigned short* gB = B + (long)(n0 + wave * 32 + lrow) * K + lcol * 8;
  unsigned short* lA0 = &As[wave * 1024];
  unsigned short* lA1 = &As[wave * 1024 + 512];
  unsigned short* lB0 = &Bs[wave * 1024];
  unsigned short* lB1 = &Bs[wave * 1024 + 512];

  for (int k0 = 0; k0 < K; k0 += 32) {
    stage16(gA + k0, lA0, lane);
    stage16(gA + k0 + 16 * K, lA1, lane);
    stage16(gB + k0, lB0, lane);
    stage16(gB + k0 + 16 * K, lB1, lane);
    __syncthreads();
    bf16x8 af[4], bfr[4];
    const int kq = (lane >> 4) * 8;
    const int rr = lane & 15;
    #pragma unroll
    for (int mi = 0; mi < 4; mi++) af[mi] = *(const bf16x8*)&As[(wr * 64 + mi * 16 + rr) * 32 + kq];
    #pragma unroll
    for (int ni = 0; ni < 4; ni++) bfr[ni] = *(const bf16x8*)&Bs[(wc * 64 + ni * 16 + rr) * 32 + kq];
    #pragma unroll
    for (int mi = 0; mi < 4; mi++)
      #pragma unroll
      for (int ni = 0; ni < 4; ni++)
        acc[mi][ni] = __builtin_amdgcn_mfma_f32_16x16x32_bf16(af[mi], bfr[ni], acc[mi][ni], 0, 0, 0);
    __syncthreads();
  }

  const int colL = lane & 15, rq = (lane >> 4) * 4;
  #pragma unroll
  for (int mi = 0; mi < 4; mi++) {
    #pragma unroll
    for (int ni = 0; ni < 4; ni++) {
      int col = n0 + wc * 64 + ni * 16 + colL;
      float bv = bias[col];
      #pragma unroll
      for (int r = 0; r < 4; r++) {
        int row = m0 + wr * 64 + mi * 16 + rq + r;
        if (row < M_valid) {
          float v = acc[mi][ni][r] + bv;
          if (OUTF) ((float*)C)[(long)row * N + col] = v;
          else      ((unsigned short*)C)[(long)row * N + col] = f2bf(v);
        }
      }
    }
  }
}

// ---------------- big GEMM: 256x256, BK=64, dbuf, one-phase-ahead pipeline ---
// C[m,n] = sum_k A[m,k]*B[n,k] + bias[n]. 8 waves (2M x 4N), wave tile 128x64.
// Phases = (mh half of wave's 8 m-frags) x (kstep of 2). All fragment reads are
// issued ONE PHASE before their consuming MFMA cluster, so the LDS unit drains
// under the matrix pipe. All fragment sets single-buffered (24 x b128).
// Staging: A(T+1) -> other buf at w1; B(T+2) -> this buf at w4; vmcnt(0) gate
// at w3 (drains loads issued >=2 phases earlier; B(T+2) stays in flight).
// Race-freedom: read@w_k is lgkm-complete before MFMA_{k+1}; any STG at w_{k+2}
// issues after the barrier following MFMA_{k+1} -> happens-before, no margins.
template <int OUTF>
__global__ __launch_bounds__(512, 2)
void gemm256(const unsigned short* __restrict__ A, const unsigned short* __restrict__ B,
             const float* __restrict__ bias, void* __restrict__ C,
             int K, int N, int M_valid) {
  extern __shared__ __align__(16) unsigned short lds[];  // 65536 ushorts (128 KiB)
  const int NT = K >> 6;          // 64-wide K tiles (K=2048 -> 32)
  const int orig = blockIdx.x;
  const int cpx = (int)gridDim.x >> 3;
  const int wgid = (orig & 7) * cpx + (orig >> 3);
  const int nt = wgid & 7;
  const int mt = wgid >> 3;
  const int m0 = mt << 8, n0 = nt << 8;
  const int tid = threadIdx.x;
  const int w = tid >> 6, l = tid & 63;
  const int wr = w >> 2, wc = w & 3;
  const int i = l & 15, kq = l >> 4;

  // fragment read constants (ush units)
  const int sw0 = ((kq ^ (i & 7)) << 3);          // kstep0 swizzled 16B block
  const int sw1 = (((4 + kq) ^ (i & 7)) << 3);    // kstep1
  const int sA = wr * 8192 + i * 64;                                  // + buf + mh*4096 + q*1024
  const int sB = 16384 + (wc >> 1) * 8192 + (wc & 1) * 4096 + i * 64; // + buf + nf*1024

  // staging constants: lane covers row w*8+(l>>3) of each 64-row group,
  // global 16B col-block (l&7)^(l>>3) (inverse swizzle on the source).
  const int sdst = w * 512;
  const unsigned short* Asrc = A + (long)(m0 + w * 8 + (l >> 3)) * K + (((l & 7) ^ (l >> 3)) << 3);
  const unsigned short* Bsrc = B + (long)(n0 + w * 8 + (l >> 3)) * K + (((l & 7) ^ (l >> 3)) << 3);

  f32x4 acc[8][4];
  #pragma unroll
  for (int a_ = 0; a_ < 8; a_++)
    #pragma unroll
    for (int b_ = 0; b_ < 4; b_++) acc[a_][b_] = (f32x4){0.f, 0.f, 0.f, 0.f};

  bf16x8 a00[4], a10[4], a11[4], a01[4];  // a[mh][ks][q]
  bf16x8 b0[4], b1[4];                    // b[ks][nf]

#define BAR __builtin_amdgcn_s_barrier()
#define VM0 asm volatile("s_waitcnt vmcnt(0)" ::: "memory")
#define VM4 asm volatile("s_waitcnt vmcnt(4)" ::: "memory")

#define RDA(dst, BUF, mh, SW) do { \
    const unsigned short* p_ = lds + (BUF) + sA + (mh) * 4096 + (SW); \
    dst[0] = *(const bf16x8*)(p_); \
    dst[1] = *(const bf16x8*)(p_ + 1024); \
    dst[2] = *(const bf16x8*)(p_ + 2048); \
    dst[3] = *(const bf16x8*)(p_ + 3072); \
  } while (0)
#define RDB(dst, BUF, SW) do { \
    const unsigned short* p_ = lds + (BUF) + sB + (SW); \
    dst[0] = *(const bf16x8*)(p_); \
    dst[1] = *(const bf16x8*)(p_ + 1024); \
    dst[2] = *(const bf16x8*)(p_ + 2048); \
    dst[3] = *(const bf16x8*)(p_ + 3072); \
  } while (0)

#define STGA(T, BUF) do { \
    const unsigned short* s_ = Asrc + (long)(T) * 64; \
    stage16(s_,                lds + (BUF) + sdst, l); \
    stage16(s_ + (long)64 * K, lds + (BUF) + 4096 + sdst, l); \
    stage16(s_ + (long)128 * K, lds + (BUF) + 8192 + sdst, l); \
    stage16(s_ + (long)192 * K, lds + (BUF) + 12288 + sdst, l); \
  } while (0)
#define STGB(T, BUF) do { \
    const unsigned short* s_ = Bsrc + (long)(T) * 64; \
    stage16(s_,                lds + (BUF) + 16384 + sdst, l); \
    stage16(s_ + (long)64 * K, lds + (BUF) + 20480 + sdst, l); \
    stage16(s_ + (long)128 * K, lds + (BUF) + 24576 + sdst, l); \
    stage16(s_ + (long)192 * K, lds + (BUF) + 28672 + sdst, l); \
  } while (0)

#define MM(mh, A_, B_) do { \
    __builtin_amdgcn_s_setprio(1); \
    _Pragma("unroll") \
    for (int q_ = 0; q_ < 4; q_++) { \
      _Pragma("unroll") \
      for (int n_ = 0; n_ < 4; n_++) \
        acc[(mh) * 4 + q_][n_] = __builtin_amdgcn_mfma_f32_16x16x32_bf16(A_[q_], B_[n_], acc[(mh) * 4 + q_][n_], 0, 0, 0); \
    } \
    __builtin_amdgcn_s_setprio(0); \
  } while (0)

// One K-tile (4 phases). BUF = this tile's buf offset, OBUF = other.
// TA: stage A(TA)->OBUF at w1 (if DOA). TB: stage B(TB)->BUF at w4 (if DOB).
// DON: read next tile's a00/b0 from OBUF at w4.
#define TILE(BUF, OBUF, TA, DOA, TB, DOB, DON) do { \
    /* w1 */ RDA(a10, BUF, 1, sw0); if (DOA) STGA(TA, OBUF); \
    BAR; MM(0, a00, b0); BAR; \
    /* w2 */ RDA(a11, BUF, 1, sw1); RDB(b1, BUF, sw1); \
    BAR; MM(1, a10, b0); BAR; \
    /* w3 */ RDA(a01, BUF, 0, sw1); VM0; \
    BAR; MM(1, a11, b1); BAR; \
    /* w4 */ if (DON) { RDA(a00, OBUF, 0, sw0); RDB(b0, OBUF, sw0); } \
    if (DOB) STGB(TB, BUF); \
    BAR; MM(0, a01, b1); BAR; \
  } while (0)

  // prologue: A(0),B(0)->buf0, B(1)->buf1 (12 loads); wait tile0; pre-read.
  STGA(0, 0); STGB(0, 0);
  STGB(1, 32768);
  VM4;   // drain tile0's 8 loads, keep B(1)'s 4 in flight
  BAR;
  RDA(a00, 0, 0, sw0);
  RDB(b0, 0, sw0);

  const int NI = NT >> 1;  // pairs
  for (int j = 0; j < NI - 1; ++j) {
    const int T0 = 2 * j;
    TILE(0, 32768, T0 + 1, 1, T0 + 2, 1, 1);
    TILE(32768, 0, T0 + 2, 1, T0 + 3, 1, 1);
  }
  // peeled last pair (tiles NT-2, NT-1): no staging beyond NT, no next reads at the very end
  TILE(0, 32768, NT - 1, 1, 0, 0, 1);
  TILE(32768, 0, 0, 0, 0, 0, 0);

#undef TILE
#undef MM
#undef STGB
#undef STGA
#undef RDB
#undef RDA
#undef VM4
#undef VM0
#undef BAR

  // epilogue
  #pragma unroll
  for (int nf = 0; nf < 4; nf++) {
    int col = n0 + wc * 64 + nf * 16 + i;
    float bv = bias[col];
    #pragma unroll
    for (int mf = 0; mf < 8; mf++) {
      int rowb = m0 + wr * 128 + mf * 16 + kq * 4;
      #pragma unroll
      for (int r = 0; r < 4; r++) {
        int row = rowb + r;
        if (row < M_valid) {
          float v = acc[mf][nf][r] + bv;
          if (OUTF) ((float*)C)[(long)row * N + col] = v;
          else      ((unsigned short*)C)[(long)row * N + col] = f2bf(v);
        }
      }
    }
  }
}

// ---------------- RoPE on K (in place, fixed positions 2 / 22) ----------------
__global__ void rope_k_kernel(unsigned short* __restrict__ kv) {
  int r = blockIdx.x;
  int c = threadIdx.x * 8;
  float pos = ((r & 31) < 16) ? 2.0f : 22.0f;
  unsigned short* p = kv + (long)r * 4096 + c;
  bf16x8 v = *(const bf16x8*)p;
  int jb = (c & 63) >> 1;
  bf16x8 o;
  #pragma unroll
  for (int t = 0; t < 4; t++) {
    float invf = __expf(-(float)(jb + t) * LN10000_32);
    float f = pos * invf;
    float s_, c_;
    sincosf(f, &s_, &c_);
    float x1 = bf2f((unsigned short)v[2 * t]);
    float x2 = bf2f((unsigned short)v[2 * t + 1]);
    o[2 * t]     = (short)f2bf(x1 * c_ - x2 * s_);
    o[2 * t + 1] = (short)f2bf(x1 * s_ + x2 * c_);
  }
  *(bf16x8*)p = o;
}

// ---------------- attention: RoPE(Q) fused + 32 keys, VALU, in place ----------
__global__ __launch_bounds__(256)
void attn_kernel(const unsigned short* __restrict__ kv, unsigned short* __restrict__ q,
                 const float2* __restrict__ tab) {
  __shared__ float Ks[2048];
  __shared__ float Vs[2048];
  const int bh = blockIdx.y;
  const int b = bh >> 5, h = bh & 31;
  const int tid = threadIdx.x;
  for (int i = tid; i < 2048; i += 256) {
    int a = i >> 6, d = i & 63;
    long off = ((long)(b * 32 + a)) * 4096 + h * 64 + d;
    Ks[i] = bf2f(kv[off]);
    Vs[i] = bf2f(kv[off + 2048]);
  }
  __syncthreads();
  int s = blockIdx.x * 256 + tid;
  if (s >= 1560) return;
  const long row = (long)b * 1560 + s;
  unsigned short* qp = q + row * 2048 + h * 64;
  float qr[64];
  #pragma unroll
  for (int i = 0; i < 8; i++) {
    bf16x8 v = *(const bf16x8*)(qp + i * 8);
    #pragma unroll
    for (int j = 0; j < 8; j++) qr[i * 8 + j] = bf2f((unsigned short)v[j]);
  }
  const float2* trow = tab + row * 32;
  #pragma unroll
  for (int j = 0; j < 32; j++) {
    float2 cs = trow[j];
    float x1 = qr[2 * j], x2 = qr[2 * j + 1];
    qr[2 * j]     = x1 * cs.x - x2 * cs.y;
    qr[2 * j + 1] = x1 * cs.y + x2 * cs.x;
  }
  float sc[32];
  float mx = -3.4e38f;
  #pragma unroll
  for (int a = 0; a < 32; a++) {
    float acc = 0.f;
    #pragma unroll
    for (int d = 0; d < 64; d++) acc = fmaf(qr[d], Ks[a * 64 + d], acc);
    acc *= 0.125f;
    sc[a] = acc;
    mx = fmaxf(mx, acc);
  }
  float sum = 0.f;
  #pragma unroll
  for (int a = 0; a < 32; a++) { float e = __expf(sc[a] - mx); sc[a] = e; sum += e; }
  float inv = 1.f / sum;
  float outr[64];
  #pragma unroll
  for (int d = 0; d < 64; d++) outr[d] = 0.f;
  #pragma unroll
  for (int a = 0; a < 32; a++) {
    float p = sc[a] * inv;
    #pragma unroll
    for (int d = 0; d < 64; d++) outr[d] = fmaf(p, Vs[a * 64 + d], outr[d]);
  }
  #pragma unroll
  for (int i = 0; i < 8; i++) {
    bf16x8 v;
    #pragma unroll
    for (int j = 0; j < 8; j++) v[j] = (short)f2bf(outr[i * 8 + j]);
    *(bf16x8*)(qp + i * 8) = v;
  }
}

// ---------------- launch ------------------------------------------------------
extern "C" void kernel_launch(void* const* d_in, const int* in_sizes, int n_in,
                              void* d_out, int out_size, void* d_ws, size_t ws_size,
                              hipStream_t stream) {
  const float* x      = (const float*)d_in[0];
  const float* ehs    = (const float*)d_in[1];
  const float* xmap   = (const float*)d_in[2];
  const float* q_w    = (const float*)d_in[3];
  const float* q_b    = (const float*)d_in[4];
  const float* kv_w   = (const float*)d_in[5];
  const float* kv_b   = (const float*)d_in[6];
  const float* proj_w = (const float*)d_in[7];
  const float* proj_b = (const float*)d_in[8];
  float* out = (float*)d_out;

  char* ws = (char*)d_ws;
  float*          mm    = (float*)(ws + 0);
  float2*         tab   = (float2*)(ws + 256);
  unsigned short* qbuf  = (unsigned short*)(ws + 8388864);
  unsigned short* kvbuf = (unsigned short*)(ws + 142606592);
  unsigned short* ehsb  = (unsigned short*)(ws + 148898048);
  unsigned short* qwb   = (unsigned short*)(ws + 150077696);
  unsigned short* kvwb  = (unsigned short*)(ws + 158466304);
  unsigned short* pwb   = (unsigned short*)(ws + 164757760);
  unsigned short* xb    = (unsigned short*)d_out;

  (void)hipFuncSetAttribute((const void*)gemm256<0>, hipFuncAttributeMaxDynamicSharedMemorySize, 131072);
  (void)hipFuncSetAttribute((const void*)gemm256<1>, hipFuncAttributeMaxDynamicSharedMemorySize, 131072);

  minmax_kernel<<<1, 256, 0, stream>>>(xmap, mm);
  pos_table_kernel<<<128, 256, 0, stream>>>(xmap, mm, tab);
  cast_x_kernel<<<32768, 256, 0, stream>>>(x, xb);
  cast_flat_kernel<<<2048, 256, 0, stream>>>(q_w, qwb, 524288);
  cast_flat_kernel<<<1536, 256, 0, stream>>>(kv_w, kvwb, 393216);
  cast_flat_kernel<<<2048, 256, 0, stream>>>(proj_w, pwb, 524288);
  cast_ehs_kernel<<<288, 256, 0, stream>>>(ehs, ehsb);

  gemm256<0><<<1024, 512, 131072, stream>>>(xb, qwb, q_b, qbuf, 2048, 2048, 32768);
  gemm_bt<0><<<dim3(6, 32), 256, 0, stream>>>(ehsb, kvwb, kv_b, kvbuf, 768, 4096, 768, 768);

  rope_k_kernel<<<672, 256, 0, stream>>>(kvbuf);

  attn_kernel<<<dim3(7, 672), 256, 0, stream>>>(kvbuf, qbuf, tab);

  gemm256<1><<<1024, 512, 131072, stream>>>(qbuf, pwb, proj_b, out, 2048, 2048, 32760);
}